// Round 7
// baseline (372.285 us; speedup 1.0000x reference)
//
#include <hip/hip_runtime.h>
#include <hip/hip_bf16.h>

#define F 32
#define S 16
#define SLICES 18      // 0..15 = fgn_w rows, 16 = fgn_b, 17 = root
#define J (SLICES * F) // 576 Y columns per node
// Y layout: uint32 Y32[n][o4][s],  o4=0..7 (channel quads), s=0..17 slices,
// element (n,o4,s,p) = bf16 pair for channels (4*o4+2p, 4*o4+2p+1).
// Node row = 288 uint32 = 1152 B contiguous; per-(n,o4) chunk = 144 B, 16B-aligned.

typedef short v8s __attribute__((ext_vector_type(8)));
typedef float v4f __attribute__((ext_vector_type(4)));

__device__ __forceinline__ float bf_lo(unsigned u) { return __uint_as_float(u << 16); }
__device__ __forceinline__ float bf_hi(unsigned u) { return __uint_as_float(u & 0xffff0000u); }
__device__ __forceinline__ unsigned short f2bf(float f) {
    __hip_bfloat16 h = __float2bfloat16(f);  // RNE
    return *(unsigned short*)&h;
}
__device__ __forceinline__ unsigned pack2(float a, float b) {
    return (unsigned)f2bf(a) | ((unsigned)f2bf(b) << 16);
}
static inline size_t align256(size_t b) { return (b + 255) & ~(size_t)255; }

// ---------------------------------------------------------------------------
// Pack both layers' weights into bf16 Wbt[j][k]: j = s*32+o, k = f.
// ---------------------------------------------------------------------------
__global__ __launch_bounds__(256) void convert_w(
    const float* __restrict__ w1, const float* __restrict__ b1, const float* __restrict__ r1,
    const float* __restrict__ w2, const float* __restrict__ b2, const float* __restrict__ r2,
    unsigned short* __restrict__ Wbt1, unsigned short* __restrict__ Wbt2)
{
    int tid = blockIdx.x * blockDim.x + threadIdx.x;
    if (tid >= 2 * J * F) return;
    const int layer = tid / (J * F);
    const int rem   = tid % (J * F);
    const int j = rem >> 5;
    const int k = rem & 31;
    const int s = j >> 5;
    const int o = j & 31;
    const float* w = layer ? w2 : w1;
    const float* b = layer ? b2 : b1;
    const float* r = layer ? r2 : r1;
    const float* slice = (s < S) ? (w + s * (F * F)) : ((s == S) ? b : r);
    unsigned short* dst = layer ? Wbt2 : Wbt1;
    dst[j * F + k] = f2bf(slice[k * F + o]);
}

// ---------------------------------------------------------------------------
// Counting sort of edges by DST -> perm + rowptr (CSR).
// ---------------------------------------------------------------------------
__global__ __launch_bounds__(256) void hist_kernel(
    const int* __restrict__ dst, int* __restrict__ cnt, int E)
{
    int e = blockIdx.x * blockDim.x + threadIdx.x;
    if (e < E) atomicAdd(&cnt[dst[e]], 1);
}

__global__ __launch_bounds__(256) void scan_partial(
    const int* __restrict__ cnt, int* __restrict__ partial, int N)
{
    const int i = blockIdx.x * 256 + threadIdx.x;
    int v = (i < N) ? cnt[i] : 0;
    #pragma unroll
    for (int off = 32; off > 0; off >>= 1) v += __shfl_down(v, off, 64);
    __shared__ int wsum[4];
    const int wave = threadIdx.x >> 6, lane = threadIdx.x & 63;
    if (lane == 0) wsum[wave] = v;
    __syncthreads();
    if (threadIdx.x == 0)
        partial[blockIdx.x] = wsum[0] + wsum[1] + wsum[2] + wsum[3];
}

__global__ void scan_top(int* __restrict__ partial, int M)
{
    const int t = threadIdx.x;  // 0..63
    int carry = 0;
    for (int base = 0; base < M; base += 64) {
        const int i = base + t;
        const int v0 = (i < M) ? partial[i] : 0;
        int v = v0;
        #pragma unroll
        for (int off = 1; off < 64; off <<= 1) {
            int u = __shfl_up(v, off, 64);
            if (t >= off) v += u;
        }
        if (i < M) partial[i] = carry + (v - v0);  // exclusive
        carry += __shfl(v, 63, 64);
    }
}

__global__ __launch_bounds__(256) void scan_final(
    const int* __restrict__ cnt, const int* __restrict__ partial,
    int* __restrict__ cursor, int* __restrict__ rowptr, int N)
{
    const int i = blockIdx.x * 256 + threadIdx.x;
    const int v0 = (i < N) ? cnt[i] : 0;
    int v = v0;
    const int wave = threadIdx.x >> 6, lane = threadIdx.x & 63;
    #pragma unroll
    for (int off = 1; off < 64; off <<= 1) {
        int u = __shfl_up(v, off, 64);
        if (lane >= off) v += u;
    }
    __shared__ int wsum[4];
    if (lane == 63) wsum[wave] = v;
    __syncthreads();
    int woff = 0;
    for (int ww = 0; ww < 4; ++ww) woff += (ww < wave) ? wsum[ww] : 0;
    if (i < N) {
        const int excl = partial[blockIdx.x] + woff + (v - v0);
        cursor[i] = excl;
        rowptr[i] = excl;
    }
}

__global__ __launch_bounds__(256) void scatter_kernel(
    const int* __restrict__ dst, int* __restrict__ cursor,
    int* __restrict__ perm, int E)
{
    int e = blockIdx.x * blockDim.x + threadIdx.x;
    if (e < E) {
        int p = atomicAdd(&cursor[dst[e]], 1);
        perm[p] = e;
    }
}

// ---------------------------------------------------------------------------
// Y GEMM via MFMA: Y(n,j) = sum_k in[n,k]*Wbt[j][k], stored in (n,o4,s) layout.
// mfma(W_frag, node_frag): D row = j, col = node. Lane's 4 regs = channels
// o0..o0+3 of slice s for node n -> ONE aligned uint2 store.
// ---------------------------------------------------------------------------
__global__ __launch_bounds__(256) void y_gemm(
    const float* __restrict__ in,           // (N,F) fp32
    const unsigned short* __restrict__ Wbt, // (J,F) bf16
    unsigned* __restrict__ Y32,             // (N,288) uint32
    int N)
{
    __shared__ unsigned short Bs[J * F];    // 36864 B
    __shared__ unsigned short As[64 * F];   // 4096 B
    const int tid = threadIdx.x;
    const int n0  = blockIdx.x * 64;

    {
        const uint4* s = (const uint4*)Wbt;
        uint4* d = (uint4*)Bs;
        #pragma unroll
        for (int i = 0; i < 9; ++i)
            d[tid + 256 * i] = s[tid + 256 * i];
    }
    {
        const int idx = tid * 8;
        const int nl  = idx >> 5;
        const int f0  = idx & 31;
        int n = n0 + nl; if (n > N - 1) n = N - 1;
        const float4* xp = (const float4*)(in + (size_t)n * F + f0);
        float4 v0 = xp[0], v1 = xp[1];
        uint4 pk;
        pk.x = pack2(v0.x, v0.y);
        pk.y = pack2(v0.z, v0.w);
        pk.z = pack2(v1.x, v1.y);
        pk.w = pack2(v1.z, v1.w);
        *(uint4*)(As + idx) = pk;
    }
    __syncthreads();

    const int w    = tid >> 6;
    const int lane = tid & 63;
    const int lid  = lane & 15;
    const int quad = lane >> 4;

    const v8s nf = *(const v8s*)(As + ((w * 16 + lid) * F + quad * 8));
    const int  n     = n0 + w * 16 + lid;
    const bool nlive = (n < N);
    unsigned* yrow = Y32 + (size_t)n * 288;

    #pragma unroll
    for (int jt = 0; jt < J / 16; ++jt) {
        const v8s wf = *(const v8s*)(Bs + ((jt * 16 + lid) * F + quad * 8));
        v4f d = {0.f, 0.f, 0.f, 0.f};
        d = __builtin_amdgcn_mfma_f32_16x16x32_bf16(wf, nf, d, 0, 0, 0);
        const int j0 = jt * 16 + quad * 4;     // 4 consecutive j, same slice
        const int s  = j0 >> 5;
        const int o4 = (j0 & 31) >> 2;
        uint2 pk;
        pk.x = pack2(d[0], d[1]);
        pk.y = pack2(d[2], d[3]);
        if (nlive)
            *(uint2*)(yrow + o4 * 36 + s * 2) = pk;
    }
}

// ---------------------------------------------------------------------------
// Fused edge aggregate + node update (NO atomics):
// 8 lanes per dst node (lane = channel quad o4). For each in-edge e:
//   acc[0..3] += sum_{s<16} ef[e,s]*Y[src](s, quad) + Y[src](16, quad)
// then + Y[n](17, quad) (root) + bias, relu, one float4 store to h.
// ---------------------------------------------------------------------------
__global__ __launch_bounds__(256) void edge_agg(
    const unsigned* __restrict__ Y32,   // (N,288)
    const float* __restrict__ ef,       // (E,S)
    const int* __restrict__ src,
    const int* __restrict__ perm,       // edges sorted by dst
    const int* __restrict__ rowptr,     // exclusive prefix of cnt
    const int* __restrict__ cnt,
    const float* __restrict__ bias,     // (F)
    float* __restrict__ h,              // (N,F) out
    int N)
{
    const int t = blockIdx.x * blockDim.x + threadIdx.x;
    if (t >= N * 8) return;
    const int n  = t >> 3;
    const int o4 = t & 7;

    // root term (slice 17 of OWN row) + bias
    const uint2 rt = *(const uint2*)(Y32 + (size_t)n * 288 + o4 * 36 + 34);
    const float4 bs = *(const float4*)(bias + 4 * o4);
    float a0 = bs.x + bf_lo(rt.x);
    float a1 = bs.y + bf_hi(rt.x);
    float a2 = bs.z + bf_lo(rt.y);
    float a3 = bs.w + bf_hi(rt.y);

    const int k0 = rowptr[n];
    const int k1 = k0 + cnt[n];
    for (int k = k0; k < k1; ++k) {
        const int e  = perm[k];
        const int sn = src[e];
        const uint4* Yr = (const uint4*)(Y32 + (size_t)sn * 288 + o4 * 36);
        const float4* efv = (const float4*)(ef + (size_t)e * S);
        const float4 c0 = efv[0], c1 = efv[1], c2 = efv[2], c3 = efv[3];
        const float cs[S] = {c0.x, c0.y, c0.z, c0.w, c1.x, c1.y, c1.z, c1.w,
                             c2.x, c2.y, c2.z, c2.w, c3.x, c3.y, c3.z, c3.w};
        #pragma unroll
        for (int i = 0; i < 8; ++i) {          // slices 2i, 2i+1
            const uint4 q = Yr[i];
            const float cA = cs[2 * i], cB = cs[2 * i + 1];
            a0 = fmaf(cA, bf_lo(q.x), a0);
            a1 = fmaf(cA, bf_hi(q.x), a1);
            a2 = fmaf(cA, bf_lo(q.y), a2);
            a3 = fmaf(cA, bf_hi(q.y), a3);
            a0 = fmaf(cB, bf_lo(q.z), a0);
            a1 = fmaf(cB, bf_hi(q.z), a1);
            a2 = fmaf(cB, bf_lo(q.w), a2);
            a3 = fmaf(cB, bf_hi(q.w), a3);
        }
        const uint2 q16 = *(const uint2*)((const unsigned*)Yr + 32);  // slice 16
        a0 += bf_lo(q16.x);
        a1 += bf_hi(q16.x);
        a2 += bf_lo(q16.y);
        a3 += bf_hi(q16.y);
    }

    float4 out;
    out.x = fmaxf(a0, 0.f);
    out.y = fmaxf(a1, 0.f);
    out.z = fmaxf(a2, 0.f);
    out.w = fmaxf(a3, 0.f);
    *(float4*)(h + (size_t)n * F + 4 * o4) = out;
}

// ---------------------------------------------------------------------------
__global__ __launch_bounds__(256) void pool_kernel(
    const float* __restrict__ h, float* __restrict__ pooled, int N)
{
    const int c = threadIdx.x & (F - 1);
    const int rowsPerBlock = 256 / F;
    float p = 0.0f;
    for (int n = blockIdx.x * rowsPerBlock + (threadIdx.x >> 5);
         n < N; n += gridDim.x * rowsPerBlock)
        p += h[(size_t)n * F + c];
    __shared__ float red[256];
    red[threadIdx.x] = p;
    __syncthreads();
    for (int off = 128; off >= F; off >>= 1) {
        if (threadIdx.x < off) red[threadIdx.x] += red[threadIdx.x + off];
        __syncthreads();
    }
    if (threadIdx.x < F) atomicAdd(&pooled[threadIdx.x], red[threadIdx.x]);
}

__global__ void final_kernel(
    const float* __restrict__ pooled, const float* __restrict__ dw,
    const float* __restrict__ db, float* __restrict__ out)
{
    const int o = threadIdx.x;
    float v = (o < F) ? pooled[o] * dw[o] : 0.0f;
    #pragma unroll
    for (int off = 32; off > 0; off >>= 1) v += __shfl_down(v, off, 64);
    if (o == 0) out[0] = v + db[0];
}

// ---------------------------------------------------------------------------
// Last-resort fallback (tiny ws): round-1 implementation.
// ---------------------------------------------------------------------------
__global__ __launch_bounds__(256, 2) void ecc_edge_slow(
    const float* __restrict__ x, const float* __restrict__ ef,
    const int* __restrict__ src, const int* __restrict__ dst,
    const float* __restrict__ W, const float* __restrict__ B,
    float* __restrict__ agg, int E)
{
    const int tid = blockIdx.x * blockDim.x + threadIdx.x;
    const bool live = (tid < E);
    const int e = live ? tid : (E - 1);
    const int sn = src[e], dn = dst[e];
    float xr[F];
    const float4* xp = (const float4*)(x + (size_t)sn * F);
    #pragma unroll
    for (int i = 0; i < F / 4; ++i) {
        float4 v = xp[i];
        xr[4*i+0] = v.x; xr[4*i+1] = v.y; xr[4*i+2] = v.z; xr[4*i+3] = v.w;
    }
    float acc[F];
    #pragma unroll
    for (int o = 0; o < F; ++o) acc[o] = 0.0f;
    const float* erow = ef + (size_t)e * S;
    for (int s = 0; s < S; ++s) {
        const float es = erow[s];
        const float* Ws = W + s * (F * F);
        #pragma unroll
        for (int f = 0; f < F; ++f) {
            const float z = es * xr[f];
            #pragma unroll
            for (int o = 0; o < F; ++o) acc[o] = fmaf(z, Ws[f * F + o], acc[o]);
        }
    }
    #pragma unroll
    for (int f = 0; f < F; ++f) {
        const float xf = xr[f];
        #pragma unroll
        for (int o = 0; o < F; ++o) acc[o] = fmaf(xf, B[f * F + o], acc[o]);
    }
    if (live) {
        float* ap = agg + (size_t)dn * F;
        #pragma unroll
        for (int o = 0; o < F; ++o) atomicAdd(ap + o, acc[o]);
    }
}

__global__ __launch_bounds__(256) void ecc_node_slow(
    const float* __restrict__ xin, const float* __restrict__ root,
    const float* __restrict__ bias, float* __restrict__ h, int N)
{
    int t = blockIdx.x * blockDim.x + threadIdx.x;
    if (t >= N * F) return;
    const int n = t >> 5, o = t & (F - 1);
    const float* xrow = xin + (size_t)n * F;
    float v = h[t] + bias[o];
    #pragma unroll
    for (int f = 0; f < F; ++f) v = fmaf(xrow[f], root[f * F + o], v);
    h[t] = fmaxf(v, 0.0f);
}

// ---------------------------------------------------------------------------
extern "C" void kernel_launch(void* const* d_in, const int* in_sizes, int n_in,
                              void* d_out, int out_size, void* d_ws, size_t ws_size,
                              hipStream_t stream) {
    const float* x      = (const float*)d_in[0];
    const float* efeat  = (const float*)d_in[1];
    const int*   src    = (const int*)d_in[2];
    const int*   dst    = (const int*)d_in[3];
    const float* fgn_w1 = (const float*)d_in[4];
    const float* fgn_b1 = (const float*)d_in[5];
    const float* root1  = (const float*)d_in[6];
    const float* bias1  = (const float*)d_in[7];
    const float* fgn_w2 = (const float*)d_in[8];
    const float* fgn_b2 = (const float*)d_in[9];
    const float* root2  = (const float*)d_in[10];
    const float* bias2  = (const float*)d_in[11];
    const float* dense_w = (const float*)d_in[12];
    const float* dense_b = (const float*)d_in[13];

    const int N = in_sizes[0] / F;
    const int E = in_sizes[2];

    const int gridP = (N + 255) / 256;

    const size_t Ybytes   = (size_t)N * 288 * 4;
    const size_t hBytes   = (size_t)N * F * sizeof(float);
    const size_t pooledB  = 256;
    const size_t cntB     = align256((size_t)N * 4);
    const size_t rowB     = align256((size_t)N * 4);
    const size_t curB     = align256((size_t)N * 4);
    const size_t partB    = align256((size_t)gridP * 4);
    const size_t permB    = align256((size_t)E * 4);
    const size_t wbtB     = align256((size_t)J * F * 2);

    // layout: Y | h1 | h2 | pooled | cnt | rowptr | cursor | partial | perm | Wbt1 | Wbt2
    const size_t offH1   = Ybytes;
    const size_t offH2   = offH1 + hBytes;
    const size_t offPool = offH2 + hBytes;
    const size_t offCnt  = offPool + pooledB;
    const size_t offRow  = offCnt + cntB;
    const size_t offCur  = offRow + rowB;
    const size_t offPart = offCur + curB;
    const size_t offPerm = offPart + partB;
    const size_t offW1   = offPerm + permB;
    const size_t offW2   = offW1 + wbtB;
    const size_t need    = offW2 + wbtB;

    const int eB         = (E + 255) / 256;
    const int nodeBlocks = (N * F + 255) / 256;

    if (ws_size >= need) {
        unsigned* Y32    = (unsigned*)d_ws;
        float*    h1     = (float*)((char*)d_ws + offH1);
        float*    h2     = (float*)((char*)d_ws + offH2);
        float*    pooled = (float*)((char*)d_ws + offPool);
        int* cnt     = (int*)((char*)d_ws + offCnt);
        int* rowptr  = (int*)((char*)d_ws + offRow);
        int* cursor  = (int*)((char*)d_ws + offCur);
        int* partial = (int*)((char*)d_ws + offPart);
        int* perm    = (int*)((char*)d_ws + offPerm);
        unsigned short* Wbt1 = (unsigned short*)((char*)d_ws + offW1);
        unsigned short* Wbt2 = (unsigned short*)((char*)d_ws + offW2);

        // zero pooled + cnt only (h rows are fully written by edge_agg)
        hipMemsetAsync((char*)d_ws + offPool, 0, pooledB + cntB, stream);

        convert_w<<<(2 * J * F + 255) / 256, 256, 0, stream>>>(
            fgn_w1, fgn_b1, root1, fgn_w2, fgn_b2, root2, Wbt1, Wbt2);

        // CSR by dst
        hist_kernel   <<<eB, 256, 0, stream>>>(dst, cnt, E);
        scan_partial  <<<gridP, 256, 0, stream>>>(cnt, partial, N);
        scan_top      <<<1, 64, 0, stream>>>(partial, gridP);
        scan_final    <<<gridP, 256, 0, stream>>>(cnt, partial, cursor, rowptr, N);
        scatter_kernel<<<eB, 256, 0, stream>>>(dst, cursor, perm, E);

        const int gemmBlocks = (N + 63) / 64;
        const int aggBlocks  = (N * 8 + 255) / 256;

        // ---- layer 1 ----
        y_gemm  <<<gemmBlocks, 256, 0, stream>>>(x, Wbt1, Y32, N);
        edge_agg<<<aggBlocks, 256, 0, stream>>>(Y32, efeat, src, perm, rowptr, cnt, bias1, h1, N);

        // ---- layer 2 ----
        y_gemm  <<<gemmBlocks, 256, 0, stream>>>(h1, Wbt2, Y32, N);
        edge_agg<<<aggBlocks, 256, 0, stream>>>(Y32, efeat, src, perm, rowptr, cnt, bias2, h2, N);

        pool_kernel <<<512, 256, 0, stream>>>(h2, pooled, N);
        final_kernel<<<1, 64, 0, stream>>>(pooled, dense_w, dense_b, (float*)d_out);
    } else {
        float* agg1   = (float*)d_ws;
        float* agg2   = agg1 + (size_t)N * F;
        float* pooled = agg2 + (size_t)N * F;
        hipMemsetAsync(d_ws, 0, 2 * hBytes + F * sizeof(float), stream);
        ecc_edge_slow<<<eB, 256, 0, stream>>>(x, efeat, src, dst, fgn_w1, fgn_b1, agg1, E);
        ecc_node_slow<<<nodeBlocks, 256, 0, stream>>>(x, root1, bias1, agg1, N);
        ecc_edge_slow<<<eB, 256, 0, stream>>>(agg1, efeat, src, dst, fgn_w2, fgn_b2, agg2, E);
        ecc_node_slow<<<nodeBlocks, 256, 0, stream>>>(agg1, root2, bias2, agg2, N);
        pool_kernel <<<512, 256, 0, stream>>>(agg2, pooled, N);
        final_kernel<<<1, 64, 0, stream>>>(pooled, dense_w, dense_b, (float*)d_out);
    }
}

// Round 8
// 253.261 us; speedup vs baseline: 1.4700x; 1.4700x over previous
//
#include <hip/hip_runtime.h>
#include <hip/hip_bf16.h>

#define F 32
#define S 16
#define SLICES 18   // 0..15 = fgn_w rows, 16 = fgn_b, 17 = root
#define J (SLICES * F)  // 576 output columns of Y

typedef short v8s __attribute__((ext_vector_type(8)));
typedef float v4f __attribute__((ext_vector_type(4)));

__device__ __forceinline__ float bf_lo(unsigned u) { return __uint_as_float(u << 16); }
__device__ __forceinline__ float bf_hi(unsigned u) { return __uint_as_float(u & 0xffff0000u); }
__device__ __forceinline__ unsigned short f2bf(float f) {
    __hip_bfloat16 h = __float2bfloat16(f);  // RNE
    return *(unsigned short*)&h;
}
__device__ __forceinline__ unsigned pack2(float a, float b) {
    return (unsigned)f2bf(a) | ((unsigned)f2bf(b) << 16);
}

// ---------------------------------------------------------------------------
// Pack both layers' weights into bf16 Wbt[j][k]:  j = s*32+o, k = f.
// ---------------------------------------------------------------------------
__global__ __launch_bounds__(256) void convert_w(
    const float* __restrict__ w1, const float* __restrict__ b1, const float* __restrict__ r1,
    const float* __restrict__ w2, const float* __restrict__ b2, const float* __restrict__ r2,
    unsigned short* __restrict__ Wbt1, unsigned short* __restrict__ Wbt2)
{
    int tid = blockIdx.x * blockDim.x + threadIdx.x;
    if (tid >= 2 * J * F) return;
    const int layer = tid / (J * F);
    const int rem   = tid % (J * F);
    const int j = rem >> 5;
    const int k = rem & 31;
    const int s = j >> 5;
    const int o = j & 31;
    const float* w = layer ? w2 : w1;
    const float* b = layer ? b2 : b1;
    const float* r = layer ? r2 : r1;
    const float* slice = (s < S) ? (w + s * (F * F)) : ((s == S) ? b : r);
    unsigned short* dst = layer ? Wbt2 : Wbt1;
    dst[j * F + k] = f2bf(slice[k * F + o]);
}

// ---------------------------------------------------------------------------
// Y GEMM via MFMA, v2:  Y[n, j] = sum_k in[n,k] * Wbt[j][k],  bf16 out.
// - W fragments live in VGPRs (9 global dwordx4 loads/lane, L2-hit, no LDS).
// - LDS holds ONLY the 4KB A-tile, in fragment order -> conflict-free b128.
// - Wave w owns j-tiles w*9..w*9+8 across ALL 64 nodes of the block tile.
// - mfma(W_frag, node_frag): D row = j, col = node; per (node,jt) the 4 quads
//   write 32B contiguous -> clean store sectors.
// ---------------------------------------------------------------------------
__global__ __launch_bounds__(256) void y_gemm(
    const float* __restrict__ in,           // (N,F) fp32
    const unsigned short* __restrict__ Wbt, // (J,F) bf16
    unsigned short* __restrict__ Y,         // (N,J) bf16
    int N)
{
    __shared__ unsigned short As[64 * F];   // 4096 B, fragment order
    const int tid  = threadIdx.x;
    const int n0   = blockIdx.x * 64;
    const int w    = tid >> 6;
    const int lane = tid & 63;
    const int lid  = lane & 15;
    const int quad = lane >> 4;

    // W fragments -> registers: wjt = w*9+jt, need Wbt[wjt*16+lid][quad*8..+7]
    v8s wf[9];
    #pragma unroll
    for (int jt = 0; jt < 9; ++jt)
        wf[jt] = *(const v8s*)(Wbt + ((size_t)(w * 9 + jt) * 16 + lid) * F + quad * 8);

    // stage A-tile in fragment order: slot (nsub*4 + kq)*16 + (nl&15) holds
    // bf16x8 of node nl = nsub*16+(nl&15), f = kq*8..kq*8+7.
    {
        const int nl = tid >> 2;            // node 0..63
        const int kq = tid & 3;             // k-quad 0..3
        int n = n0 + nl; if (n > N - 1) n = N - 1;
        const float4* xp = (const float4*)(in + (size_t)n * F + kq * 8);
        float4 v0 = xp[0], v1 = xp[1];
        uint4 pk;
        pk.x = pack2(v0.x, v0.y);
        pk.y = pack2(v0.z, v0.w);
        pk.z = pack2(v1.x, v1.y);
        pk.w = pack2(v1.z, v1.w);
        const int slot = ((nl >> 4) * 4 + kq) * 16 + (nl & 15);
        *(uint4*)(As + slot * 8) = pk;
    }
    __syncthreads();

    // A fragments: one per 16-node subtile
    v8s af[4];
    #pragma unroll
    for (int ns = 0; ns < 4; ++ns)
        af[ns] = *(const v8s*)(As + (((ns * 4 + quad) * 16) + lid) * 8);

    #pragma unroll
    for (int jt = 0; jt < 9; ++jt) {
        const int wjt = w * 9 + jt;
        #pragma unroll
        for (int ns = 0; ns < 4; ++ns) {
            v4f d = {0.f, 0.f, 0.f, 0.f};
            d = __builtin_amdgcn_mfma_f32_16x16x32_bf16(wf[jt], af[ns], d, 0, 0, 0);
            const int n = n0 + ns * 16 + lid;
            uint2 pk;
            pk.x = pack2(d[0], d[1]);
            pk.y = pack2(d[2], d[3]);
            if (n < N)
                *(uint2*)(Y + (size_t)n * J + wjt * 16 + quad * 4) = pk;
        }
    }
}

// ---------------------------------------------------------------------------
// Edge gather: msg[e,o] = Y[src,16,o] + sum_{s<16} ef[e,s]*Y[src,s,o]
// lane = (edge, o-pair); scatter-add to agg[dst].
// ---------------------------------------------------------------------------
__global__ __launch_bounds__(256) void edge_gather(
    const unsigned* __restrict__ Yu,  // (N, J/2) bf16-pairs
    const float* __restrict__ ef,     // (E,S)
    const int* __restrict__ src,
    const int* __restrict__ dst,
    float* __restrict__ agg,          // (N,F), pre-zeroed
    int E)
{
    const int gid = blockIdx.x * blockDim.x + threadIdx.x;
    const int e = gid >> 4;
    if (e >= E) return;
    const int o2 = gid & 15;
    const int sn = src[e], dn = dst[e];

    const unsigned* Yr = Yu + (size_t)sn * (J / 2) + o2;
    const float4* efv = (const float4*)(ef + (size_t)e * S);
    float4 c0 = efv[0], c1 = efv[1], c2 = efv[2], c3 = efv[3];
    const float cs[S] = {c0.x, c0.y, c0.z, c0.w, c1.x, c1.y, c1.z, c1.w,
                         c2.x, c2.y, c2.z, c2.w, c3.x, c3.y, c3.z, c3.w};

    unsigned u = Yr[S * (F / 2)];  // slice 16 = fgn bias term
    float m0 = bf_lo(u), m1 = bf_hi(u);
    #pragma unroll
    for (int s = 0; s < S; ++s) {
        unsigned v = Yr[s * (F / 2)];
        m0 = fmaf(cs[s], bf_lo(v), m0);
        m1 = fmaf(cs[s], bf_hi(v), m1);
    }
    float* ap = agg + (size_t)dn * F + 2 * o2;
    atomicAdd(ap,     m0);
    atomicAdd(ap + 1, m1);
}

// ---------------------------------------------------------------------------
// Node fuse: h[n,o] = relu(agg[n,o] + Y[n, slice17, o] + bias[o])
// ---------------------------------------------------------------------------
__global__ __launch_bounds__(256) void node_fuse(
    const unsigned short* __restrict__ Yb,
    const float* __restrict__ bias,
    float* __restrict__ h, int N)
{
    const int t = blockIdx.x * blockDim.x + threadIdx.x;
    if (t >= N * F) return;
    const int n = t >> 5, o = t & (F - 1);
    const float rt = __uint_as_float(((unsigned)Yb[(size_t)n * J + 17 * F + o]) << 16);
    h[t] = fmaxf(h[t] + rt + bias[o], 0.f);
}

// ---------------------------------------------------------------------------
__global__ __launch_bounds__(256) void pool_kernel(
    const float* __restrict__ h, float* __restrict__ pooled, int N)
{
    const int c = threadIdx.x & (F - 1);
    const int rowsPerBlock = 256 / F;
    float p = 0.0f;
    for (int n = blockIdx.x * rowsPerBlock + (threadIdx.x >> 5);
         n < N; n += gridDim.x * rowsPerBlock)
        p += h[(size_t)n * F + c];
    __shared__ float red[256];
    red[threadIdx.x] = p;
    __syncthreads();
    for (int off = 128; off >= F; off >>= 1) {
        if (threadIdx.x < off) red[threadIdx.x] += red[threadIdx.x + off];
        __syncthreads();
    }
    if (threadIdx.x < F) atomicAdd(&pooled[threadIdx.x], red[threadIdx.x]);
}

__global__ void final_kernel(
    const float* __restrict__ pooled, const float* __restrict__ dw,
    const float* __restrict__ db, float* __restrict__ out)
{
    const int o = threadIdx.x;
    float v = (o < F) ? pooled[o] * dw[o] : 0.0f;
    #pragma unroll
    for (int off = 32; off > 0; off >>= 1) v += __shfl_down(v, off, 64);
    if (o == 0) out[0] = v + db[0];
}

// ---------------------------------------------------------------------------
// Last-resort fallback (tiny ws): round-1 implementation.
// ---------------------------------------------------------------------------
__global__ __launch_bounds__(256, 2) void ecc_edge_slow(
    const float* __restrict__ x, const float* __restrict__ ef,
    const int* __restrict__ src, const int* __restrict__ dst,
    const float* __restrict__ W, const float* __restrict__ B,
    float* __restrict__ agg, int E)
{
    const int tid = blockIdx.x * blockDim.x + threadIdx.x;
    const bool live = (tid < E);
    const int e = live ? tid : (E - 1);
    const int sn = src[e], dn = dst[e];
    float xr[F];
    const float4* xp = (const float4*)(x + (size_t)sn * F);
    #pragma unroll
    for (int i = 0; i < F / 4; ++i) {
        float4 v = xp[i];
        xr[4*i+0] = v.x; xr[4*i+1] = v.y; xr[4*i+2] = v.z; xr[4*i+3] = v.w;
    }
    float acc[F];
    #pragma unroll
    for (int o = 0; o < F; ++o) acc[o] = 0.0f;
    const float* erow = ef + (size_t)e * S;
    for (int s = 0; s < S; ++s) {
        const float es = erow[s];
        const float* Ws = W + s * (F * F);
        #pragma unroll
        for (int f = 0; f < F; ++f) {
            const float z = es * xr[f];
            #pragma unroll
            for (int o = 0; o < F; ++o) acc[o] = fmaf(z, Ws[f * F + o], acc[o]);
        }
    }
    #pragma unroll
    for (int f = 0; f < F; ++f) {
        const float xf = xr[f];
        #pragma unroll
        for (int o = 0; o < F; ++o) acc[o] = fmaf(xf, B[f * F + o], acc[o]);
    }
    if (live) {
        float* ap = agg + (size_t)dn * F;
        #pragma unroll
        for (int o = 0; o < F; ++o) atomicAdd(ap + o, acc[o]);
    }
}

__global__ __launch_bounds__(256) void ecc_node_slow(
    const float* __restrict__ xin, const float* __restrict__ root,
    const float* __restrict__ bias, float* __restrict__ h, int N)
{
    int t = blockIdx.x * blockDim.x + threadIdx.x;
    if (t >= N * F) return;
    const int n = t >> 5, o = t & (F - 1);
    const float* xrow = xin + (size_t)n * F;
    float v = h[t] + bias[o];
    #pragma unroll
    for (int f = 0; f < F; ++f) v = fmaf(xrow[f], root[f * F + o], v);
    h[t] = fmaxf(v, 0.0f);
}

// ---------------------------------------------------------------------------
extern "C" void kernel_launch(void* const* d_in, const int* in_sizes, int n_in,
                              void* d_out, int out_size, void* d_ws, size_t ws_size,
                              hipStream_t stream) {
    const float* x      = (const float*)d_in[0];
    const float* efeat  = (const float*)d_in[1];
    const int*   src    = (const int*)d_in[2];
    const int*   dst    = (const int*)d_in[3];
    const float* fgn_w1 = (const float*)d_in[4];
    const float* fgn_b1 = (const float*)d_in[5];
    const float* root1  = (const float*)d_in[6];
    const float* bias1  = (const float*)d_in[7];
    const float* fgn_w2 = (const float*)d_in[8];
    const float* fgn_b2 = (const float*)d_in[9];
    const float* root2  = (const float*)d_in[10];
    const float* bias2  = (const float*)d_in[11];
    const float* dense_w = (const float*)d_in[12];
    const float* dense_b = (const float*)d_in[13];

    const int N = in_sizes[0] / F;
    const int E = in_sizes[2];

    const size_t Ybytes   = (size_t)N * J * 2;           // bf16 Y
    const size_t aggBytes = (size_t)N * F * sizeof(float);
    const size_t pooledB  = 256;
    const size_t wbtBytes = (size_t)J * F * 2;           // 36864 B each
    const size_t need     = Ybytes + 2 * aggBytes + pooledB + 2 * wbtBytes;

    const int eB         = (E + 255) / 256;
    const int nodeBlocks = (N * F + 255) / 256;

    if (ws_size >= need) {
        unsigned*       Yu = (unsigned*)d_ws;
        unsigned short* Yb = (unsigned short*)d_ws;
        float* agg1   = (float*)((char*)d_ws + Ybytes);
        float* agg2   = agg1 + (size_t)N * F;
        float* pooled = agg2 + (size_t)N * F;
        unsigned short* Wbt1 = (unsigned short*)((char*)d_ws + Ybytes + 2 * aggBytes + pooledB);
        unsigned short* Wbt2 = Wbt1 + J * F;

        hipMemsetAsync((char*)d_ws + Ybytes, 0, 2 * aggBytes + F * sizeof(float), stream);

        convert_w<<<(2 * J * F + 255) / 256, 256, 0, stream>>>(
            fgn_w1, fgn_b1, root1, fgn_w2, fgn_b2, root2, Wbt1, Wbt2);

        const int gemmBlocks = (N + 63) / 64;
        const int edgeBlocks = (E * (F / 2) + 255) / 256;

        // ---- layer 1 ----
        y_gemm<<<gemmBlocks, 256, 0, stream>>>(x, Wbt1, Yb, N);
        edge_gather<<<edgeBlocks, 256, 0, stream>>>(Yu, efeat, src, dst, agg1, E);
        node_fuse<<<nodeBlocks, 256, 0, stream>>>(Yb, bias1, agg1, N);  // agg1 -> h1

        // ---- layer 2 ----
        y_gemm<<<gemmBlocks, 256, 0, stream>>>(agg1, Wbt2, Yb, N);
        edge_gather<<<edgeBlocks, 256, 0, stream>>>(Yu, efeat, src, dst, agg2, E);
        node_fuse<<<nodeBlocks, 256, 0, stream>>>(Yb, bias2, agg2, N);  // agg2 -> h2

        pool_kernel <<<512, 256, 0, stream>>>(agg2, pooled, N);
        final_kernel<<<1, 64, 0, stream>>>(pooled, dense_w, dense_b, (float*)d_out);
    } else {
        float* agg1   = (float*)d_ws;
        float* agg2   = agg1 + (size_t)N * F;
        float* pooled = agg2 + (size_t)N * F;
        hipMemsetAsync(d_ws, 0, 2 * aggBytes + F * sizeof(float), stream);
        ecc_edge_slow<<<eB, 256, 0, stream>>>(x, efeat, src, dst, fgn_w1, fgn_b1, agg1, E);
        ecc_node_slow<<<nodeBlocks, 256, 0, stream>>>(x, root1, bias1, agg1, N);
        ecc_edge_slow<<<eB, 256, 0, stream>>>(agg1, efeat, src, dst, fgn_w2, fgn_b2, agg2, E);
        ecc_node_slow<<<nodeBlocks, 256, 0, stream>>>(agg1, root2, bias2, agg2, N);
        pool_kernel <<<512, 256, 0, stream>>>(agg2, pooled, N);
        final_kernel<<<1, 64, 0, stream>>>(pooled, dense_w, dense_b, (float*)d_out);
    }
}

// Round 9
// 217.471 us; speedup vs baseline: 1.7119x; 1.1646x over previous
//
#include <hip/hip_runtime.h>
#include <hip/hip_bf16.h>
#include <hip/hip_fp16.h>

#define F 32
#define S 16
#define SLICES 18   // 0..15 = fgn_w rows, 16 = fgn_b, 17 = root
#define J (SLICES * F)  // 576 output columns of Y

typedef short v8s __attribute__((ext_vector_type(8)));
typedef float v4f __attribute__((ext_vector_type(4)));

__device__ __forceinline__ float bf_lo(unsigned u) { return __uint_as_float(u << 16); }
__device__ __forceinline__ float bf_hi(unsigned u) { return __uint_as_float(u & 0xffff0000u); }
__device__ __forceinline__ unsigned short f2bf(float f) {
    __hip_bfloat16 h = __float2bfloat16(f);  // RNE
    return *(unsigned short*)&h;
}
__device__ __forceinline__ unsigned pack2(float a, float b) {
    return (unsigned)f2bf(a) | ((unsigned)f2bf(b) << 16);
}

// ---------------------------------------------------------------------------
// Pack both layers' weights into bf16 Wbt[j][k]:  j = s*32+o, k = f.
// ---------------------------------------------------------------------------
__global__ __launch_bounds__(256) void convert_w(
    const float* __restrict__ w1, const float* __restrict__ b1, const float* __restrict__ r1,
    const float* __restrict__ w2, const float* __restrict__ b2, const float* __restrict__ r2,
    unsigned short* __restrict__ Wbt1, unsigned short* __restrict__ Wbt2)
{
    int tid = blockIdx.x * blockDim.x + threadIdx.x;
    if (tid >= 2 * J * F) return;
    const int layer = tid / (J * F);
    const int rem   = tid % (J * F);
    const int j = rem >> 5;
    const int k = rem & 31;
    const int s = j >> 5;
    const int o = j & 31;
    const float* w = layer ? w2 : w1;
    const float* b = layer ? b2 : b1;
    const float* r = layer ? r2 : r1;
    const float* slice = (s < S) ? (w + s * (F * F)) : ((s == S) ? b : r);
    unsigned short* dst = layer ? Wbt2 : Wbt1;
    dst[j * F + k] = f2bf(slice[k * F + o]);
}

// ---------------------------------------------------------------------------
// Y GEMM via MFMA:  Y[n, j] = sum_k h[n,k] * Wbt[j][k],  bf16 out.
// Layer 1: h = in (fp32). Layer 2 (aggIn != null): h = relu(agg + Y[.,17] +
// biasPrev) computed inline during A-staging (node_fuse fused away).
// In-place Y read (slice 17) is safe: each block reads only its own 64 rows
// before __syncthreads and writes them after.
// W fragments in VGPRs (L2-hit dwordx4), LDS holds only the 4KB A-tile in
// fragment order. mfma(W_frag, node_frag): D row = j, col = node.
// ---------------------------------------------------------------------------
__global__ __launch_bounds__(256) void y_gemm(
    const float* __restrict__ inF,          // (N,F) fp32 (layer 1) or null
    const __half2* __restrict__ aggIn,      // (N,16) fp16 pairs (layer 2) or null
    const float* __restrict__ biasPrev,     // (F) layer-1 bias (layer 2 path)
    const unsigned short* __restrict__ Wbt, // (J,F) bf16
    unsigned short* __restrict__ Y,         // (N,J) bf16 (also Yprev for fused path)
    int N)
{
    __shared__ unsigned short As[64 * F];   // 4096 B, fragment order
    const int tid  = threadIdx.x;
    const int n0   = blockIdx.x * 64;
    const int w    = tid >> 6;
    const int lane = tid & 63;
    const int lid  = lane & 15;
    const int quad = lane >> 4;

    // W fragments -> registers
    v8s wf[9];
    #pragma unroll
    for (int jt = 0; jt < 9; ++jt)
        wf[jt] = *(const v8s*)(Wbt + ((size_t)(w * 9 + jt) * 16 + lid) * F + quad * 8);

    // stage A-tile in fragment order
    {
        const int nl = tid >> 2;            // node 0..63
        const int kq = tid & 3;             // k-quad 0..3 (channels kq*8..+7)
        int n = n0 + nl; if (n > N - 1) n = N - 1;
        uint4 pk;
        if (aggIn) {
            const uint4 au = *(const uint4*)(aggIn + (size_t)n * 16 + kq * 4);
            const uint4 ru = *(const uint4*)((const unsigned*)Y + (size_t)n * (J / 2) + 272 + kq * 4);
            const float4 b0 = *(const float4*)(biasPrev + kq * 8);
            const float4 b1 = *(const float4*)(biasPrev + kq * 8 + 4);
            const float2 a0 = __half22float2(*(const __half2*)&au.x);
            const float2 a1 = __half22float2(*(const __half2*)&au.y);
            const float2 a2 = __half22float2(*(const __half2*)&au.z);
            const float2 a3 = __half22float2(*(const __half2*)&au.w);
            const float h0 = fmaxf(a0.x + bf_lo(ru.x) + b0.x, 0.f);
            const float h1 = fmaxf(a0.y + bf_hi(ru.x) + b0.y, 0.f);
            const float h2 = fmaxf(a1.x + bf_lo(ru.y) + b0.z, 0.f);
            const float h3 = fmaxf(a1.y + bf_hi(ru.y) + b0.w, 0.f);
            const float h4 = fmaxf(a2.x + bf_lo(ru.z) + b1.x, 0.f);
            const float h5 = fmaxf(a2.y + bf_hi(ru.z) + b1.y, 0.f);
            const float h6 = fmaxf(a3.x + bf_lo(ru.w) + b1.z, 0.f);
            const float h7 = fmaxf(a3.y + bf_hi(ru.w) + b1.w, 0.f);
            pk.x = pack2(h0, h1);
            pk.y = pack2(h2, h3);
            pk.z = pack2(h4, h5);
            pk.w = pack2(h6, h7);
        } else {
            const float4* xp = (const float4*)(inF + (size_t)n * F + kq * 8);
            float4 v0 = xp[0], v1 = xp[1];
            pk.x = pack2(v0.x, v0.y);
            pk.y = pack2(v0.z, v0.w);
            pk.z = pack2(v1.x, v1.y);
            pk.w = pack2(v1.z, v1.w);
        }
        const int slot = ((nl >> 4) * 4 + kq) * 16 + (nl & 15);
        *(uint4*)(As + slot * 8) = pk;
    }
    __syncthreads();

    v8s af[4];
    #pragma unroll
    for (int ns = 0; ns < 4; ++ns)
        af[ns] = *(const v8s*)(As + (((ns * 4 + quad) * 16) + lid) * 8);

    #pragma unroll
    for (int jt = 0; jt < 9; ++jt) {
        const int wjt = w * 9 + jt;
        #pragma unroll
        for (int ns = 0; ns < 4; ++ns) {
            v4f d = {0.f, 0.f, 0.f, 0.f};
            d = __builtin_amdgcn_mfma_f32_16x16x32_bf16(wf[jt], af[ns], d, 0, 0, 0);
            const int n = n0 + ns * 16 + lid;
            uint2 pk;
            pk.x = pack2(d[0], d[1]);
            pk.y = pack2(d[2], d[3]);
            if (n < N)
                *(uint2*)(Y + (size_t)n * J + wjt * 16 + quad * 4) = pk;
        }
    }
}

// ---------------------------------------------------------------------------
// Edge gather: msg[e,o] = Y[src,16,o] + sum_{s<16} ef[e,s]*Y[src,s,o]
// lane = (edge, o-pair); ONE packed-fp16 atomic per lane to agg[dst]
// (global_atomic_pk_add_f16 -> half the RMW count + write-back of 2x fp32).
// ---------------------------------------------------------------------------
__global__ __launch_bounds__(256) void edge_gather(
    const unsigned* __restrict__ Yu,  // (N, J/2) bf16-pairs
    const float* __restrict__ ef,     // (E,S)
    const int* __restrict__ src,
    const int* __restrict__ dst,
    __half2* __restrict__ agg,        // (N,16) fp16 pairs, pre-zeroed
    int E)
{
    const int gid = blockIdx.x * blockDim.x + threadIdx.x;
    const int e = gid >> 4;
    if (e >= E) return;
    const int o2 = gid & 15;
    const int sn = src[e], dn = dst[e];

    const unsigned* Yr = Yu + (size_t)sn * (J / 2) + o2;
    const float4* efv = (const float4*)(ef + (size_t)e * S);
    float4 c0 = efv[0], c1 = efv[1], c2 = efv[2], c3 = efv[3];
    const float cs[S] = {c0.x, c0.y, c0.z, c0.w, c1.x, c1.y, c1.z, c1.w,
                         c2.x, c2.y, c2.z, c2.w, c3.x, c3.y, c3.z, c3.w};

    unsigned u = Yr[S * (F / 2)];  // slice 16 = fgn bias term
    float m0 = bf_lo(u), m1 = bf_hi(u);
    #pragma unroll
    for (int s = 0; s < S; ++s) {
        unsigned v = Yr[s * (F / 2)];
        m0 = fmaf(cs[s], bf_lo(v), m0);
        m1 = fmaf(cs[s], bf_hi(v), m1);
    }
    unsafeAtomicAdd(agg + (size_t)dn * 16 + o2, __floats2half2_rn(m0, m1));
}

// ---------------------------------------------------------------------------
// Fused node update + pool: pooled[c] = sum_n relu(agg2[n,c] + Y[n,17,c] + bias[c])
// thread = (row-slot, channel-pair); grid-stride over rows.
// ---------------------------------------------------------------------------
__global__ __launch_bounds__(256) void pool_fuse(
    const __half2* __restrict__ agg,  // (N,16) fp16 pairs
    const unsigned* __restrict__ Yu,  // (N, J/2)
    const float* __restrict__ bias,
    float* __restrict__ pooled,       // (F), pre-zeroed
    int N)
{
    const int c2 = threadIdx.x & 15;
    const float2 b = *(const float2*)(bias + 2 * c2);
    float p0 = 0.f, p1 = 0.f;
    for (int n = blockIdx.x * 16 + (threadIdx.x >> 4); n < N; n += gridDim.x * 16) {
        const float2 a = __half22float2(agg[(size_t)n * 16 + c2]);
        const unsigned r = Yu[(size_t)n * (J / 2) + 272 + c2];
        p0 += fmaxf(a.x + bf_lo(r) + b.x, 0.f);
        p1 += fmaxf(a.y + bf_hi(r) + b.y, 0.f);
    }
    __shared__ float r0[256], r1[256];
    r0[threadIdx.x] = p0; r1[threadIdx.x] = p1;
    __syncthreads();
    for (int off = 128; off >= 16; off >>= 1) {
        if (threadIdx.x < off) {
            r0[threadIdx.x] += r0[threadIdx.x + off];
            r1[threadIdx.x] += r1[threadIdx.x + off];
        }
        __syncthreads();
    }
    if (threadIdx.x < 16) {
        atomicAdd(&pooled[2 * threadIdx.x],     r0[threadIdx.x]);
        atomicAdd(&pooled[2 * threadIdx.x + 1], r1[threadIdx.x]);
    }
}

__global__ void final_kernel(
    const float* __restrict__ pooled, const float* __restrict__ dw,
    const float* __restrict__ db, float* __restrict__ out)
{
    const int o = threadIdx.x;
    float v = (o < F) ? pooled[o] * dw[o] : 0.0f;
    #pragma unroll
    for (int off = 32; off > 0; off >>= 1) v += __shfl_down(v, off, 64);
    if (o == 0) out[0] = v + db[0];
}

// ---------------------------------------------------------------------------
// Last-resort fallback (tiny ws): round-1 implementation.
// ---------------------------------------------------------------------------
__global__ __launch_bounds__(256, 2) void ecc_edge_slow(
    const float* __restrict__ x, const float* __restrict__ ef,
    const int* __restrict__ src, const int* __restrict__ dst,
    const float* __restrict__ W, const float* __restrict__ B,
    float* __restrict__ agg, int E)
{
    const int tid = blockIdx.x * blockDim.x + threadIdx.x;
    const bool live = (tid < E);
    const int e = live ? tid : (E - 1);
    const int sn = src[e], dn = dst[e];
    float xr[F];
    const float4* xp = (const float4*)(x + (size_t)sn * F);
    #pragma unroll
    for (int i = 0; i < F / 4; ++i) {
        float4 v = xp[i];
        xr[4*i+0] = v.x; xr[4*i+1] = v.y; xr[4*i+2] = v.z; xr[4*i+3] = v.w;
    }
    float acc[F];
    #pragma unroll
    for (int o = 0; o < F; ++o) acc[o] = 0.0f;
    const float* erow = ef + (size_t)e * S;
    for (int s = 0; s < S; ++s) {
        const float es = erow[s];
        const float* Ws = W + s * (F * F);
        #pragma unroll
        for (int f = 0; f < F; ++f) {
            const float z = es * xr[f];
            #pragma unroll
            for (int o = 0; o < F; ++o) acc[o] = fmaf(z, Ws[f * F + o], acc[o]);
        }
    }
    #pragma unroll
    for (int f = 0; f < F; ++f) {
        const float xf = xr[f];
        #pragma unroll
        for (int o = 0; o < F; ++o) acc[o] = fmaf(xf, B[f * F + o], acc[o]);
    }
    if (live) {
        float* ap = agg + (size_t)dn * F;
        #pragma unroll
        for (int o = 0; o < F; ++o) atomicAdd(ap + o, acc[o]);
    }
}

__global__ __launch_bounds__(256) void ecc_node_slow(
    const float* __restrict__ xin, const float* __restrict__ root,
    const float* __restrict__ bias, float* __restrict__ h, int N)
{
    int t = blockIdx.x * blockDim.x + threadIdx.x;
    if (t >= N * F) return;
    const int n = t >> 5, o = t & (F - 1);
    const float* xrow = xin + (size_t)n * F;
    float v = h[t] + bias[o];
    #pragma unroll
    for (int f = 0; f < F; ++f) v = fmaf(xrow[f], root[f * F + o], v);
    h[t] = fmaxf(v, 0.0f);
}

__global__ __launch_bounds__(256) void pool_kernel(
    const float* __restrict__ h, float* __restrict__ pooled, int N)
{
    const int c = threadIdx.x & (F - 1);
    const int rowsPerBlock = 256 / F;
    float p = 0.0f;
    for (int n = blockIdx.x * rowsPerBlock + (threadIdx.x >> 5);
         n < N; n += gridDim.x * rowsPerBlock)
        p += h[(size_t)n * F + c];
    __shared__ float red[256];
    red[threadIdx.x] = p;
    __syncthreads();
    for (int off = 128; off >= F; off >>= 1) {
        if (threadIdx.x < off) red[threadIdx.x] += red[threadIdx.x + off];
        __syncthreads();
    }
    if (threadIdx.x < F) atomicAdd(&pooled[threadIdx.x], red[threadIdx.x]);
}

// ---------------------------------------------------------------------------
extern "C" void kernel_launch(void* const* d_in, const int* in_sizes, int n_in,
                              void* d_out, int out_size, void* d_ws, size_t ws_size,
                              hipStream_t stream) {
    const float* x      = (const float*)d_in[0];
    const float* efeat  = (const float*)d_in[1];
    const int*   src    = (const int*)d_in[2];
    const int*   dst    = (const int*)d_in[3];
    const float* fgn_w1 = (const float*)d_in[4];
    const float* fgn_b1 = (const float*)d_in[5];
    const float* root1  = (const float*)d_in[6];
    const float* bias1  = (const float*)d_in[7];
    const float* fgn_w2 = (const float*)d_in[8];
    const float* fgn_b2 = (const float*)d_in[9];
    const float* root2  = (const float*)d_in[10];
    const float* bias2  = (const float*)d_in[11];
    const float* dense_w = (const float*)d_in[12];
    const float* dense_b = (const float*)d_in[13];

    const int N = in_sizes[0] / F;
    const int E = in_sizes[2];

    const size_t Ybytes   = (size_t)N * J * 2;         // bf16 Y  (57.6 MB)
    const size_t aggB     = (size_t)N * 16 * 4;        // fp16x2 agg (3.2 MB)
    const size_t pooledB  = 256;
    const size_t wbtB     = (size_t)J * F * 2;         // 36864 B each
    // layout: Y | agg1 | agg2 | pooled | Wbt1 | Wbt2
    const size_t offA1   = Ybytes;
    const size_t offA2   = offA1 + aggB;
    const size_t offPool = offA2 + aggB;
    const size_t offW1   = offPool + pooledB;
    const size_t offW2   = offW1 + wbtB;
    const size_t need    = offW2 + wbtB;

    const int eB         = (E + 255) / 256;
    const int nodeBlocks = (N * F + 255) / 256;

    if (ws_size >= need) {
        unsigned*       Yu = (unsigned*)d_ws;
        unsigned short* Yb = (unsigned short*)d_ws;
        __half2* agg1   = (__half2*)((char*)d_ws + offA1);
        __half2* agg2   = (__half2*)((char*)d_ws + offA2);
        float*   pooled = (float*)((char*)d_ws + offPool);
        unsigned short* Wbt1 = (unsigned short*)((char*)d_ws + offW1);
        unsigned short* Wbt2 = (unsigned short*)((char*)d_ws + offW2);

        // zero agg1 + agg2 + pooled in one contiguous memset
        hipMemsetAsync((char*)d_ws + offA1, 0, 2 * aggB + pooledB, stream);

        convert_w<<<(2 * J * F + 255) / 256, 256, 0, stream>>>(
            fgn_w1, fgn_b1, root1, fgn_w2, fgn_b2, root2, Wbt1, Wbt2);

        const int gemmBlocks = (N + 63) / 64;
        const int edgeBlocks = (E * (F / 2) + 255) / 256;

        // ---- layer 1 ----
        y_gemm<<<gemmBlocks, 256, 0, stream>>>(x, nullptr, nullptr, Wbt1, Yb, N);
        edge_gather<<<edgeBlocks, 256, 0, stream>>>(Yu, efeat, src, dst, agg1, E);

        // ---- layer 2 (node_fuse1 fused into A-staging, in-place Y) ----
        y_gemm<<<gemmBlocks, 256, 0, stream>>>(nullptr, agg1, bias1, Wbt2, Yb, N);
        edge_gather<<<edgeBlocks, 256, 0, stream>>>(Yu, efeat, src, dst, agg2, E);

        // ---- node_fuse2 + pool fused ----
        pool_fuse<<<256, 256, 0, stream>>>(agg2, Yu, bias2, pooled, N);
        final_kernel<<<1, 64, 0, stream>>>(pooled, dense_w, dense_b, (float*)d_out);
    } else {
        float* agg1   = (float*)d_ws;
        float* agg2   = agg1 + (size_t)N * F;
        float* pooled = agg2 + (size_t)N * F;
        hipMemsetAsync(d_ws, 0, (2 * (size_t)N * F + F) * sizeof(float), stream);
        ecc_edge_slow<<<eB, 256, 0, stream>>>(x, efeat, src, dst, fgn_w1, fgn_b1, agg1, E);
        ecc_node_slow<<<nodeBlocks, 256, 0, stream>>>(x, root1, bias1, agg1, N);
        ecc_edge_slow<<<eB, 256, 0, stream>>>(agg1, efeat, src, dst, fgn_w2, fgn_b2, agg2, E);
        ecc_node_slow<<<nodeBlocks, 256, 0, stream>>>(agg1, root2, bias2, agg2, N);
        pool_kernel <<<512, 256, 0, stream>>>(agg2, pooled, N);
        final_kernel<<<1, 64, 0, stream>>>(pooled, dense_w, dense_b, (float*)d_out);
    }
}

// Round 10
// 215.301 us; speedup vs baseline: 1.7291x; 1.0101x over previous
//
#include <hip/hip_runtime.h>
#include <hip/hip_bf16.h>
#include <hip/hip_fp16.h>

#define F 32
#define S 16
#define K2 544          // 16 ef slices * 32 + 32 bias slice
#define NT_EDGE 1024    // edge_msg grid blocks

typedef short v8s __attribute__((ext_vector_type(8)));
typedef float v4f __attribute__((ext_vector_type(4)));

__device__ __forceinline__ float bf_lo(unsigned u) { return __uint_as_float(u << 16); }
__device__ __forceinline__ float bf_hi(unsigned u) { return __uint_as_float(u & 0xffff0000u); }
__device__ __forceinline__ unsigned short f2bf(float f) {
    __hip_bfloat16 h = __float2bfloat16(f);  // RNE
    return *(unsigned short*)&h;
}
__device__ __forceinline__ unsigned pack2(float a, float b) {
    return (unsigned)f2bf(a) | ((unsigned)f2bf(b) << 16);
}

// ---------------------------------------------------------------------------
// Weight prep per layer:
//  W2t[o][k] (32 x 544 bf16): k=(s,f) -> s<16: fgn_w[s, f*32+o]; s==16: fgn_b[f*32+o]
//  Rt[o][f]  (32 x 32 bf16):  root[f*32+o]
// ---------------------------------------------------------------------------
__global__ __launch_bounds__(256) void convert_w2(
    const float* __restrict__ w1, const float* __restrict__ b1, const float* __restrict__ r1,
    const float* __restrict__ w2, const float* __restrict__ b2, const float* __restrict__ r2,
    unsigned short* __restrict__ W2t1, unsigned short* __restrict__ W2t2,
    unsigned short* __restrict__ Rt1,  unsigned short* __restrict__ Rt2)
{
    const int PER = 32 * K2 + 32 * 32;  // 18432 per layer
    int tid = blockIdx.x * blockDim.x + threadIdx.x;
    if (tid >= 2 * PER) return;
    const int layer = tid / PER;
    const int rem   = tid % PER;
    const float* w = layer ? w2 : w1;
    const float* b = layer ? b2 : b1;
    const float* r = layer ? r2 : r1;
    if (rem < 32 * K2) {
        const int o = rem / K2;
        const int k = rem % K2;
        const int s = k >> 5, f = k & 31;
        const float v = (s < S) ? w[s * (F * F) + f * F + o] : b[f * F + o];
        (layer ? W2t2 : W2t1)[o * K2 + k] = f2bf(v);
    } else {
        const int q = rem - 32 * K2;
        const int o = q >> 5, f = q & 31;
        (layer ? Rt2 : Rt1)[o * F + f] = f2bf(r[f * F + o]);
    }
}

// ---------------------------------------------------------------------------
// edge_msg: per 16-edge tile per wave, build Z-fragments in registers and
// MFMA against VGPR-resident W2t fragments.
//   msg[e,o] = sum_{s<16} ef[e,s]*(x[src[e]] row) @ fgn_w[s] + x[src[e]] @ fgn_b
// D = mfma(W2t_frag, Z_frag): col = edge (lid), row = o -> lane holds
// o = quad*4..+3 (acc0) and 16+quad*4..+3 (acc1) for its own edge ->
// 4 packed-fp16 atomics per lane into agg[dst].
// ---------------------------------------------------------------------------
__global__ __launch_bounds__(256) void edge_msg(
    const float* __restrict__ xin,          // (N,F) fp32 node feats
    const float* __restrict__ ef,           // (E,S)
    const int* __restrict__ src,
    const int* __restrict__ dst,
    const unsigned short* __restrict__ W2t, // (32,K2) bf16
    __half2* __restrict__ agg,              // (N,16) fp16 pairs, pre-zeroed
    int E)
{
    const int tid  = threadIdx.x;
    const int w    = tid >> 6;
    const int lane = tid & 63;
    const int lid  = lane & 15;
    const int quad = lane >> 4;

    // W2t fragments -> VGPRs (L2-resident; reused across all tiles of the wave)
    v8s wa0[17], wa1[17];
    #pragma unroll
    for (int ck = 0; ck < 17; ++ck) {
        wa0[ck] = *(const v8s*)(W2t + (size_t)lid * K2        + ck * 32 + quad * 8);
        wa1[ck] = *(const v8s*)(W2t + (size_t)(16 + lid) * K2 + ck * 32 + quad * 8);
    }

    const int nTiles = (E + 15) >> 4;
    for (int tile = blockIdx.x * 4 + w; tile < nTiles; tile += NT_EDGE * 4) {
        const int  slot = tile * 16 + lid;
        const bool live = (slot < E);
        const int  e    = live ? slot : 0;
        const int  sn   = src[e];
        const int  dn   = dst[e];

        // x[src] row, this quad's 8 channels
        const float4* xp = (const float4*)(xin + (size_t)sn * F + quad * 8);
        const float4 xv0 = xp[0], xv1 = xp[1];

        // ef row (16 coeffs)
        const float4* efv = (const float4*)(ef + (size_t)e * S);
        const float4 c0 = efv[0], c1 = efv[1], c2 = efv[2], c3 = efv[3];
        const float cs[S] = {c0.x, c0.y, c0.z, c0.w, c1.x, c1.y, c1.z, c1.w,
                             c2.x, c2.y, c2.z, c2.w, c3.x, c3.y, c3.z, c3.w};

        v4f acc0 = {0.f, 0.f, 0.f, 0.f};
        v4f acc1 = {0.f, 0.f, 0.f, 0.f};

        #pragma unroll
        for (int ck = 0; ck < S; ++ck) {
            const float sc = cs[ck];
            union { v8s s8; uint4 u4; } fr;
            fr.u4.x = pack2(sc * xv0.x, sc * xv0.y);
            fr.u4.y = pack2(sc * xv0.z, sc * xv0.w);
            fr.u4.z = pack2(sc * xv1.x, sc * xv1.y);
            fr.u4.w = pack2(sc * xv1.z, sc * xv1.w);
            acc0 = __builtin_amdgcn_mfma_f32_16x16x32_bf16(wa0[ck], fr.s8, acc0, 0, 0, 0);
            acc1 = __builtin_amdgcn_mfma_f32_16x16x32_bf16(wa1[ck], fr.s8, acc1, 0, 0, 0);
        }
        {   // bias slice: Z = x itself
            union { v8s s8; uint4 u4; } fr;
            fr.u4.x = pack2(xv0.x, xv0.y);
            fr.u4.y = pack2(xv0.z, xv0.w);
            fr.u4.z = pack2(xv1.x, xv1.y);
            fr.u4.w = pack2(xv1.z, xv1.w);
            acc0 = __builtin_amdgcn_mfma_f32_16x16x32_bf16(wa0[16], fr.s8, acc0, 0, 0, 0);
            acc1 = __builtin_amdgcn_mfma_f32_16x16x32_bf16(wa1[16], fr.s8, acc1, 0, 0, 0);
        }

        if (live) {
            __half2* ap = agg + (size_t)dn * 16;
            unsafeAtomicAdd(ap + quad * 2,         __floats2half2_rn(acc0[0], acc0[1]));
            unsafeAtomicAdd(ap + quad * 2 + 1,     __floats2half2_rn(acc0[2], acc0[3]));
            unsafeAtomicAdd(ap + 8 + quad * 2,     __floats2half2_rn(acc1[0], acc1[1]));
            unsafeAtomicAdd(ap + 8 + quad * 2 + 1, __floats2half2_rn(acc1[2], acc1[3]));
        }
    }
}

// ---------------------------------------------------------------------------
// root_fuse: h[n,o] = relu(agg[n,o] + sum_f in[n,f]*root[f,o] + bias[o])
// MFMA over K=32; block = 64 nodes; wave w: j-tile = w&1, node-subtiles (w>>1).
// ---------------------------------------------------------------------------
__global__ __launch_bounds__(256) void root_fuse(
    const float* __restrict__ in,          // (N,F) fp32
    const __half2* __restrict__ agg,       // (N,16)
    const unsigned short* __restrict__ Rt, // (32,32) bf16 [o][f]
    const float* __restrict__ bias,
    float* __restrict__ h,                 // (N,F) fp32 out
    int N)
{
    __shared__ unsigned short As[64 * F];  // 4096 B, fragment order
    const int tid  = threadIdx.x;
    const int n0   = blockIdx.x * 64;
    const int w    = tid >> 6;
    const int lane = tid & 63;
    const int lid  = lane & 15;
    const int quad = lane >> 4;

    {   // stage 64-node bf16 tile in fragment order
        const int nl = tid >> 2;
        const int kq = tid & 3;
        int n = n0 + nl; if (n > N - 1) n = N - 1;
        const float4* xp = (const float4*)(in + (size_t)n * F + kq * 8);
        float4 v0 = xp[0], v1 = xp[1];
        uint4 pk;
        pk.x = pack2(v0.x, v0.y);
        pk.y = pack2(v0.z, v0.w);
        pk.z = pack2(v1.x, v1.y);
        pk.w = pack2(v1.z, v1.w);
        const int slot = ((nl >> 4) * 4 + kq) * 16 + (nl & 15);
        *(uint4*)(As + slot * 8) = pk;
    }
    __syncthreads();

    const int jt  = w & 1;
    const int ns0 = (w >> 1) * 2;
    const v8s rf = *(const v8s*)(Rt + (size_t)(jt * 16 + lid) * F + quad * 8);
    const int o0 = jt * 16 + quad * 4;
    const float4 bs = *(const float4*)(bias + o0);

    #pragma unroll
    for (int i = 0; i < 2; ++i) {
        const int ns = ns0 + i;
        const v8s af = *(const v8s*)(As + (((ns * 4 + quad) * 16) + lid) * 8);
        v4f d = {0.f, 0.f, 0.f, 0.f};
        d = __builtin_amdgcn_mfma_f32_16x16x32_bf16(rf, af, d, 0, 0, 0);
        const int n = n0 + ns * 16 + lid;
        if (n < N) {
            const uint2 au = *(const uint2*)(agg + (size_t)n * 16 + o0 / 2);
            const float2 a01 = __half22float2(*(const __half2*)&au.x);
            const float2 a23 = __half22float2(*(const __half2*)&au.y);
            float4 hv;
            hv.x = fmaxf(d[0] + a01.x + bs.x, 0.f);
            hv.y = fmaxf(d[1] + a01.y + bs.y, 0.f);
            hv.z = fmaxf(d[2] + a23.x + bs.z, 0.f);
            hv.w = fmaxf(d[3] + a23.y + bs.w, 0.f);
            *(float4*)(h + (size_t)n * F + o0) = hv;
        }
    }
}

// ---------------------------------------------------------------------------
__global__ __launch_bounds__(256) void pool_kernel(
    const float* __restrict__ h, float* __restrict__ pooled, int N)
{
    const int c = threadIdx.x & (F - 1);
    const int rowsPerBlock = 256 / F;
    float p = 0.0f;
    for (int n = blockIdx.x * rowsPerBlock + (threadIdx.x >> 5);
         n < N; n += gridDim.x * rowsPerBlock)
        p += h[(size_t)n * F + c];
    __shared__ float red[256];
    red[threadIdx.x] = p;
    __syncthreads();
    for (int off = 128; off >= F; off >>= 1) {
        if (threadIdx.x < off) red[threadIdx.x] += red[threadIdx.x + off];
        __syncthreads();
    }
    if (threadIdx.x < F) atomicAdd(&pooled[threadIdx.x], red[threadIdx.x]);
}

__global__ void final_kernel(
    const float* __restrict__ pooled, const float* __restrict__ dw,
    const float* __restrict__ db, float* __restrict__ out)
{
    const int o = threadIdx.x;
    float v = (o < F) ? pooled[o] * dw[o] : 0.0f;
    #pragma unroll
    for (int off = 32; off > 0; off >>= 1) v += __shfl_down(v, off, 64);
    if (o == 0) out[0] = v + db[0];
}

// ---------------------------------------------------------------------------
// Last-resort fallback (tiny ws): round-1 implementation.
// ---------------------------------------------------------------------------
__global__ __launch_bounds__(256, 2) void ecc_edge_slow(
    const float* __restrict__ x, const float* __restrict__ ef,
    const int* __restrict__ src, const int* __restrict__ dst,
    const float* __restrict__ W, const float* __restrict__ B,
    float* __restrict__ agg, int E)
{
    const int tid = blockIdx.x * blockDim.x + threadIdx.x;
    const bool live = (tid < E);
    const int e = live ? tid : (E - 1);
    const int sn = src[e], dn = dst[e];
    float xr[F];
    const float4* xp = (const float4*)(x + (size_t)sn * F);
    #pragma unroll
    for (int i = 0; i < F / 4; ++i) {
        float4 v = xp[i];
        xr[4*i+0] = v.x; xr[4*i+1] = v.y; xr[4*i+2] = v.z; xr[4*i+3] = v.w;
    }
    float acc[F];
    #pragma unroll
    for (int o = 0; o < F; ++o) acc[o] = 0.0f;
    const float* erow = ef + (size_t)e * S;
    for (int s = 0; s < S; ++s) {
        const float es = erow[s];
        const float* Ws = W + s * (F * F);
        #pragma unroll
        for (int f = 0; f < F; ++f) {
            const float z = es * xr[f];
            #pragma unroll
            for (int o = 0; o < F; ++o) acc[o] = fmaf(z, Ws[f * F + o], acc[o]);
        }
    }
    #pragma unroll
    for (int f = 0; f < F; ++f) {
        const float xf = xr[f];
        #pragma unroll
        for (int o = 0; o < F; ++o) acc[o] = fmaf(xf, B[f * F + o], acc[o]);
    }
    if (live) {
        float* ap = agg + (size_t)dn * F;
        #pragma unroll
        for (int o = 0; o < F; ++o) atomicAdd(ap + o, acc[o]);
    }
}

__global__ __launch_bounds__(256) void ecc_node_slow(
    const float* __restrict__ xin, const float* __restrict__ root,
    const float* __restrict__ bias, float* __restrict__ h, int N)
{
    int t = blockIdx.x * blockDim.x + threadIdx.x;
    if (t >= N * F) return;
    const int n = t >> 5, o = t & (F - 1);
    const float* xrow = xin + (size_t)n * F;
    float v = h[t] + bias[o];
    #pragma unroll
    for (int f = 0; f < F; ++f) v = fmaf(xrow[f], root[f * F + o], v);
    h[t] = fmaxf(v, 0.0f);
}

// ---------------------------------------------------------------------------
extern "C" void kernel_launch(void* const* d_in, const int* in_sizes, int n_in,
                              void* d_out, int out_size, void* d_ws, size_t ws_size,
                              hipStream_t stream) {
    const float* x      = (const float*)d_in[0];
    const float* efeat  = (const float*)d_in[1];
    const int*   src    = (const int*)d_in[2];
    const int*   dst    = (const int*)d_in[3];
    const float* fgn_w1 = (const float*)d_in[4];
    const float* fgn_b1 = (const float*)d_in[5];
    const float* root1  = (const float*)d_in[6];
    const float* bias1  = (const float*)d_in[7];
    const float* fgn_w2 = (const float*)d_in[8];
    const float* fgn_b2 = (const float*)d_in[9];
    const float* root2  = (const float*)d_in[10];
    const float* bias2  = (const float*)d_in[11];
    const float* dense_w = (const float*)d_in[12];
    const float* dense_b = (const float*)d_in[13];

    const int N = in_sizes[0] / F;
    const int E = in_sizes[2];

    const size_t aggB   = (size_t)N * 16 * 4;      // fp16x2 agg (3.2 MB)
    const size_t pooledB = 256;
    const size_t hB     = (size_t)N * F * 4;       // fp32 h (6.4 MB)
    const size_t w2tB   = (size_t)32 * K2 * 2;     // 34816 B
    const size_t rtB    = (size_t)32 * 32 * 2;     // 2048 B
    // layout: agg1 | agg2 | pooled | h1 | h2 | W2t1 | W2t2 | Rt1 | Rt2
    const size_t offA1 = 0;
    const size_t offA2 = offA1 + aggB;
    const size_t offPl = offA2 + aggB;
    const size_t offH1 = offPl + pooledB;
    const size_t offH2 = offH1 + hB;
    const size_t offW1 = offH2 + hB;
    const size_t offW2 = offW1 + w2tB;
    const size_t offR1 = offW2 + w2tB;
    const size_t offR2 = offR1 + rtB;
    const size_t need  = offR2 + rtB;

    const int eB         = (E + 255) / 256;
    const int nodeBlocks = (N * F + 255) / 256;

    if (ws_size >= need) {
        __half2* agg1   = (__half2*)((char*)d_ws + offA1);
        __half2* agg2   = (__half2*)((char*)d_ws + offA2);
        float*   pooled = (float*)((char*)d_ws + offPl);
        float*   h1     = (float*)((char*)d_ws + offH1);
        float*   h2     = (float*)((char*)d_ws + offH2);
        unsigned short* W2t1 = (unsigned short*)((char*)d_ws + offW1);
        unsigned short* W2t2 = (unsigned short*)((char*)d_ws + offW2);
        unsigned short* Rt1  = (unsigned short*)((char*)d_ws + offR1);
        unsigned short* Rt2  = (unsigned short*)((char*)d_ws + offR2);

        // zero agg1 + agg2 + pooled (contiguous)
        hipMemsetAsync(d_ws, 0, 2 * aggB + pooledB, stream);

        convert_w2<<<(2 * (32 * K2 + 32 * 32) + 255) / 256, 256, 0, stream>>>(
            fgn_w1, fgn_b1, root1, fgn_w2, fgn_b2, root2, W2t1, W2t2, Rt1, Rt2);

        const int rootBlocks = (N + 63) / 64;

        // ---- layer 1 ----
        edge_msg <<<NT_EDGE, 256, 0, stream>>>(x, efeat, src, dst, W2t1, agg1, E);
        root_fuse<<<rootBlocks, 256, 0, stream>>>(x, agg1, Rt1, bias1, h1, N);

        // ---- layer 2 ----
        edge_msg <<<NT_EDGE, 256, 0, stream>>>(h1, efeat, src, dst, W2t2, agg2, E);
        root_fuse<<<rootBlocks, 256, 0, stream>>>(h1, agg2, Rt2, bias2, h2, N);

        pool_kernel <<<512, 256, 0, stream>>>(h2, pooled, N);
        final_kernel<<<1, 64, 0, stream>>>(pooled, dense_w, dense_b, (float*)d_out);
    } else {
        float* agg1   = (float*)d_ws;
        float* agg2   = agg1 + (size_t)N * F;
        float* pooled = agg2 + (size_t)N * F;
        hipMemsetAsync(d_ws, 0, (2 * (size_t)N * F + F) * sizeof(float), stream);
        ecc_edge_slow<<<eB, 256, 0, stream>>>(x, efeat, src, dst, fgn_w1, fgn_b1, agg1, E);
        ecc_node_slow<<<nodeBlocks, 256, 0, stream>>>(x, root1, bias1, agg1, N);
        ecc_edge_slow<<<eB, 256, 0, stream>>>(agg1, efeat, src, dst, fgn_w2, fgn_b2, agg2, E);
        ecc_node_slow<<<nodeBlocks, 256, 0, stream>>>(agg1, root2, bias2, agg2, N);
        pool_kernel <<<512, 256, 0, stream>>>(agg2, pooled, N);
        final_kernel<<<1, 64, 0, stream>>>(pooled, dense_w, dense_b, (float*)d_out);
    }
}